// Round 4
// baseline (228.708 us; speedup 1.0000x reference)
//
#include <hip/hip_runtime.h>
#include <math.h>

#define BB 64
#define LL 256
#define DD 1024
#define NDPAD 512   // padded anti-diagonal count per batch (511 real + 1 pad)
#define BK 32
#define LOG2E 1.4426950408889634f
#define LN2   0.6931471805599453f

typedef __attribute__((ext_vector_type(8))) short short8v;
typedef __attribute__((ext_vector_type(4))) float float4v;

__device__ __forceinline__ unsigned short f2bf(float f) {
    unsigned u = __float_as_uint(f);
    unsigned r = (u + 0x7fffu + ((u >> 16) & 1u)) >> 16;   // RNE
    return (unsigned short)r;
}
__device__ __forceinline__ float bf2f(unsigned short u) {
    return __uint_as_float(((unsigned)u) << 16);
}

// ---------- prep: squared norms + fp32->bf16 copies (one block per row) ----------
__global__ __launch_bounds__(256) void prep_kernel(const float* __restrict__ S,
                                                   const float* __restrict__ T,
                                                   unsigned short* __restrict__ S16,
                                                   unsigned short* __restrict__ T16,
                                                   float* __restrict__ s2,
                                                   float* __restrict__ t2) {
    int rid = blockIdx.x;
    int t = threadIdx.x;
    const float* src;
    unsigned short* dst;
    float* nrm;
    if (rid < BB * LL) {
        src = S + (size_t)rid * DD; dst = S16 + (size_t)rid * DD; nrm = s2 + rid;
    } else {
        int r2 = rid - BB * LL;
        src = T + (size_t)r2 * DD; dst = T16 + (size_t)r2 * DD; nrm = t2 + r2;
    }
    float4 v = ((const float4*)src)[t];
    float s = v.x * v.x + v.y * v.y + v.z * v.z + v.w * v.w;
    ushort4 h;
    h.x = f2bf(v.x); h.y = f2bf(v.y); h.z = f2bf(v.z); h.w = f2bf(v.w);
    ((ushort4*)dst)[t] = h;
    #pragma unroll
    for (int off = 32; off; off >>= 1) s += __shfl_down(s, off, 64);
    __shared__ float red[4];
    if ((t & 63) == 0) red[t >> 6] = s;
    __syncthreads();
    if (t == 0) *nrm = red[0] + red[1] + red[2] + red[3];
}

// ---------- sqnorm only (fallback path) ----------
__global__ __launch_bounds__(256) void sqnorm_kernel(const float* __restrict__ x,
                                                     float* __restrict__ out) {
    int row = blockIdx.x;
    const float* p = x + (size_t)row * DD;
    int t = threadIdx.x;
    float4 v = ((const float4*)p)[t];
    float s = v.x * v.x + v.y * v.y + v.z * v.z + v.w * v.w;
    #pragma unroll
    for (int off = 32; off; off >>= 1) s += __shfl_down(s, off, 64);
    __shared__ float red[4];
    if ((t & 63) == 0) red[t >> 6] = s;
    __syncthreads();
    if (t == 0) out[row] = red[0] + red[1] + red[2] + red[3];
}

// ---------- MFMA bf16 distance GEMM: 128x128 tile, BK=32, 4 waves ----------
// Epilogue stores bf16 dist * LOG2E in diag-major layout [b][i+j][j], 512-diag stride.
__global__ __launch_bounds__(256) void distmf_kernel(const unsigned short* __restrict__ S16,
                                                     const unsigned short* __restrict__ T16,
                                                     const float* __restrict__ s2,
                                                     const float* __restrict__ t2,
                                                     unsigned short* __restrict__ Dd) {
    __shared__ unsigned short lds[2][2][128 * BK];   // [buf][A/B], 32 KB
    const int b    = blockIdx.y;
    const int tile = blockIdx.x;
    const int i0 = (tile & 1) * 128;
    const int j0 = (tile >> 1) * 128;
    const int tid = threadIdx.x, w = tid >> 6, lane = tid & 63;
    const int wr = w >> 1, wc = w & 1;

    const unsigned short* Sg = S16 + ((size_t)b * LL + i0) * DD;
    const unsigned short* Tg = T16 + ((size_t)b * LL + j0) * DD;

    const int sr   = w * 16 + (lane >> 2);
    const int skb0 = lane & 3;

    float4v acc[4][4];
    const float4v fzero = {0.f, 0.f, 0.f, 0.f};
    #pragma unroll
    for (int mi = 0; mi < 4; ++mi)
        #pragma unroll
        for (int ni = 0; ni < 4; ++ni) acc[mi][ni] = fzero;

    auto stage = [&](int buf, int k0) {
        #pragma unroll
        for (int n = 0; n < 2; ++n) {
            int r  = n * 64 + sr;
            int kb = skb0 ^ (r & 3);          // pre-swizzled GLOBAL source (LDS stays linear)
            __builtin_amdgcn_global_load_lds(
                (const __attribute__((address_space(1))) void*)(Sg + (size_t)r * DD + k0 + kb * 8),
                (__attribute__((address_space(3))) void*)(&lds[buf][0][(n * 64 + w * 16) * BK]),
                16, 0, 0);
            __builtin_amdgcn_global_load_lds(
                (const __attribute__((address_space(1))) void*)(Tg + (size_t)r * DD + k0 + kb * 8),
                (__attribute__((address_space(3))) void*)(&lds[buf][1][(n * 64 + w * 16) * BK]),
                16, 0, 0);
        }
    };

    stage(0, 0);
    for (int kt = 0; kt < 32; ++kt) {
        int cur = kt & 1;
        __syncthreads();
        if (kt < 31) stage(cur ^ 1, (kt + 1) * BK);

        const unsigned short* LA = &lds[cur][0][0];
        const unsigned short* LB = &lds[cur][1][0];
        short8v af[4], bf[4];
        #pragma unroll
        for (int mi = 0; mi < 4; ++mi) {
            int row = wr * 64 + mi * 16 + (lane & 15);
            int kb  = (lane >> 4) ^ (row & 3);
            af[mi] = *(const short8v*)(LA + row * BK + kb * 8);
        }
        #pragma unroll
        for (int ni = 0; ni < 4; ++ni) {
            int row = wc * 64 + ni * 16 + (lane & 15);
            int kb  = (lane >> 4) ^ (row & 3);
            bf[ni] = *(const short8v*)(LB + row * BK + kb * 8);
        }
        #pragma unroll
        for (int mi = 0; mi < 4; ++mi)
            #pragma unroll
            for (int ni = 0; ni < 4; ++ni)
                acc[mi][ni] = __builtin_amdgcn_mfma_f32_16x16x32_bf16(af[mi], bf[ni],
                                                                      acc[mi][ni], 0, 0, 0);
    }

    const int r0 = (lane >> 4) * 4;
    const int cf = lane & 15;
    unsigned short* Db = Dd + (size_t)b * NDPAD * 256;
    #pragma unroll
    for (int mi = 0; mi < 4; ++mi) {
        #pragma unroll
        for (int ni = 0; ni < 4; ++ni) {
            int j = j0 + wc * 64 + ni * 16 + cf;
            float tj = t2[b * LL + j];
            #pragma unroll
            for (int rg = 0; rg < 4; ++rg) {
                int i = i0 + wr * 64 + mi * 16 + r0 + rg;
                float sq = s2[b * LL + i] + tj - 2.0f * acc[mi][ni][rg];
                float dv = sqrtf(fmaxf(sq, 1e-12f));
                Db[(size_t)(i + j) * 256 + j] = f2bf(dv * LOG2E);
            }
        }
    }
}

// ---------- fp32 tiled distance GEMM (fallback if ws too small) ----------
__global__ __launch_bounds__(256) void dist_kernel(const float* __restrict__ S,
                                                   const float* __restrict__ T,
                                                   const float* __restrict__ s2,
                                                   const float* __restrict__ t2,
                                                   unsigned short* __restrict__ Dd) {
    int b  = blockIdx.z;
    int i0 = blockIdx.y * 64;
    int j0 = blockIdx.x * 64;
    const float* Sb = S + (size_t)b * LL * DD;
    const float* Tb = T + (size_t)b * LL * DD;
    __shared__ float sA[16][65];
    __shared__ float sB[16][65];
    int tid = threadIdx.x;
    int tx = tid & 15, ty = tid >> 4, lk = tid & 15, lm = tid >> 4;
    float acc[4][4] = {};
    for (int k0 = 0; k0 < DD; k0 += 16) {
        #pragma unroll
        for (int r = 0; r < 4; ++r) {
            int m = lm + 16 * r;
            sA[lk][m] = Sb[(size_t)(i0 + m) * DD + k0 + lk];
            sB[lk][m] = Tb[(size_t)(j0 + m) * DD + k0 + lk];
        }
        __syncthreads();
        #pragma unroll
        for (int kk = 0; kk < 16; ++kk) {
            float a[4], bv[4];
            #pragma unroll
            for (int ii = 0; ii < 4; ++ii) a[ii] = sA[kk][ty * 4 + ii];
            #pragma unroll
            for (int jj = 0; jj < 4; ++jj) bv[jj] = sB[kk][tx * 4 + jj];
            #pragma unroll
            for (int ii = 0; ii < 4; ++ii)
                #pragma unroll
                for (int jj = 0; jj < 4; ++jj)
                    acc[ii][jj] += a[ii] * bv[jj];
        }
        __syncthreads();
    }
    #pragma unroll
    for (int ii = 0; ii < 4; ++ii) {
        int p = i0 + ty * 4 + ii;
        float si = s2[b * LL + p];
        #pragma unroll
        for (int jj = 0; jj < 4; ++jj) {
            int q = j0 + tx * 4 + jj;
            float sq = si + t2[b * LL + q] - 2.0f * acc[ii][jj];
            float dv = sqrtf(fmaxf(sq, 1e-12f));
            Dd[((size_t)b * NDPAD + (p + q)) * 256 + q] = f2bf(dv * LOG2E);
        }
    }
}

// ---------- soft-DTW DP: one wave64 per batch, LDS-pipelined dist stream ----------
// Base-2 domain: dist was pre-scaled by log2(e); result scaled back by ln2.
__device__ __forceinline__ float sdtw_cell2(bool valid, float dval, float a, float u, float l) {
    float m = fminf(a, fminf(u, l));
    float s = exp2f(m - a) + exp2f(m - u) + exp2f(m - l);
    float r = dval + m - log2f(s);
    return valid ? r : INFINITY;
}

__global__ __launch_bounds__(64) void sdtw_kernel(const unsigned short* __restrict__ Dg,
                                                  float* __restrict__ res) {
    __shared__ unsigned short sd[4][16 * 256];   // 4 chunk buffers x 8 KB = 32 KB
    const int b = blockIdx.x;
    const int lane = threadIdx.x;
    const float INF = INFINITY;
    const unsigned short* Db = Dg + (size_t)b * NDPAD * 256;

    // async-prefetch chunk c (16 diagonals) into sd[c&3]:
    // 8 x global_load_lds width-16; LDS dest = uniform base + lane*16 (HW pattern)
    auto prefetch = [&](int c) {
        #pragma unroll
        for (int q = 0; q < 8; ++q) {
            __builtin_amdgcn_global_load_lds(
                (const __attribute__((address_space(1))) void*)(Db + (size_t)c * 4096 + q * 512 + lane * 8),
                (__attribute__((address_space(3))) void*)(&sd[c & 3][q * 512]),
                16, 0, 0);
        }
    };

    prefetch(0);
    prefetch(1);

    float rm1_0 = INF, rm1_1 = INF, rm1_2 = INF, rm1_3 = INF;
    float rm2_0 = INF, rm2_1 = INF, rm2_2 = INF, rm2_3 = INF;
    float p2carry = (lane == 0) ? 0.0f : INF;    // p2(d) = p1(d-1); seed for d=2
    const int jb = 4 * lane + 1;

    for (int c = 0; c < 32; ++c) {
        if (c < 30) {
            prefetch(c + 2);                                  // 24 in flight
            asm volatile("s_waitcnt vmcnt(16)" ::: "memory"); // chunk c landed
        } else if (c == 30) {
            asm volatile("s_waitcnt vmcnt(8)" ::: "memory");
        } else {
            asm volatile("s_waitcnt vmcnt(0)" ::: "memory");
        }
        __builtin_amdgcn_sched_barrier(0);

        const unsigned short* Lp = &sd[c & 3][0];
        ushort4 pkts[16];
        #pragma unroll
        for (int q = 0; q < 16; ++q)
            pkts[q] = *(const ushort4*)(Lp + q * 256 + 4 * lane);

        const int vbase = 16 * c + 1 - jb;       // i-1 for slot0 at q=0
        #pragma unroll
        for (int q = 0; q < 16; ++q) {
            float p1 = __shfl_up(rm1_3, 1);
            p1 = (lane == 0) ? INF : p1;
            float p2 = p2carry;
            p2carry = p1;
            float d0 = bf2f(pkts[q].x), d1 = bf2f(pkts[q].y);
            float d2v = bf2f(pkts[q].z), d3 = bf2f(pkts[q].w);
            float rc0 = sdtw_cell2((unsigned)(vbase + q)     < 256u, d0,  p2,    rm1_0, p1);
            float rc1 = sdtw_cell2((unsigned)(vbase + q - 1) < 256u, d1,  rm2_0, rm1_1, rm1_0);
            float rc2 = sdtw_cell2((unsigned)(vbase + q - 2) < 256u, d2v, rm2_1, rm1_2, rm1_1);
            float rc3 = sdtw_cell2((unsigned)(vbase + q - 3) < 256u, d3,  rm2_2, rm1_3, rm1_2);
            rm2_0 = rm1_0; rm2_1 = rm1_1; rm2_2 = rm1_2; rm2_3 = rm1_3;
            rm1_0 = rc0;  rm1_1 = rc1;  rm1_2 = rc2;  rm1_3 = rc3;
        }
    }
    // last real diagonal d=512 sits in rm2 after the dummy d=513 step
    if (lane == 63) res[b] = rm2_3 * LN2;
}

// ---------- final mean over batches ----------
__global__ void reduce_kernel(const float* __restrict__ res, float* __restrict__ out) {
    int t = threadIdx.x;
    float v = res[t];
    #pragma unroll
    for (int off = 32; off; off >>= 1) v += __shfl_down(v, off, 64);
    if (t == 0) out[0] = v * (1.0f / BB);
}

extern "C" void kernel_launch(void* const* d_in, const int* in_sizes, int n_in,
                              void* d_out, int out_size, void* d_ws, size_t ws_size,
                              hipStream_t stream) {
    const float* S = (const float*)d_in[0];
    const float* T = (const float*)d_in[1];

    const size_t nElem  = (size_t)BB * LL * DD;                 // 16,777,216
    const size_t nDiag  = (size_t)BB * NDPAD * 256;             // 8,388,608 ushorts
    const size_t needBF = nElem * 2 * sizeof(unsigned short)
                        + nDiag * sizeof(unsigned short)
                        + ((size_t)2 * BB * LL + BB) * sizeof(float);

    if (ws_size >= needBF) {
        unsigned short* diag = (unsigned short*)d_ws;
        unsigned short* S16  = diag + nDiag;
        unsigned short* T16  = S16 + nElem;
        float* s2  = (float*)(T16 + nElem);
        float* t2  = s2 + BB * LL;
        float* rsv = t2 + BB * LL;

        prep_kernel<<<2 * BB * LL, 256, 0, stream>>>(S, T, S16, T16, s2, t2);
        distmf_kernel<<<dim3(4, BB), 256, 0, stream>>>(S16, T16, s2, t2, diag);
        sdtw_kernel<<<BB, 64, 0, stream>>>(diag, rsv);
        reduce_kernel<<<1, 64, 0, stream>>>(rsv, (float*)d_out);
    } else {
        unsigned short* diag = (unsigned short*)d_ws;
        float* s2  = (float*)(diag + nDiag);
        float* t2  = s2 + BB * LL;
        float* rsv = t2 + BB * LL;

        sqnorm_kernel<<<BB * LL, 256, 0, stream>>>(S, s2);
        sqnorm_kernel<<<BB * LL, 256, 0, stream>>>(T, t2);
        dim3 g(LL / 64, LL / 64, BB);
        dist_kernel<<<g, 256, 0, stream>>>(S, T, s2, t2, diag);
        sdtw_kernel<<<BB, 64, 0, stream>>>(diag, rsv);
        reduce_kernel<<<1, 64, 0, stream>>>(rsv, (float*)d_out);
    }
}

// Round 5
// 141.833 us; speedup vs baseline: 1.6125x; 1.6125x over previous
//
#include <hip/hip_runtime.h>
#include <math.h>

#define BB 64
#define LL 256
#define DD 1024
#define NDPAD 512   // padded anti-diagonal count per batch (511 real + 1 pad)
#define BK 32
#define LOG2E 1.4426950408889634f
#define LN2   0.6931471805599453f

typedef __attribute__((ext_vector_type(8))) short short8v;
typedef __attribute__((ext_vector_type(4))) float float4v;

__device__ __forceinline__ unsigned short f2bf(float f) {
    unsigned u = __float_as_uint(f);
    unsigned r = (u + 0x7fffu + ((u >> 16) & 1u)) >> 16;   // RNE
    return (unsigned short)r;
}
__device__ __forceinline__ float bf2f(unsigned short u) {
    return __uint_as_float(((unsigned)u) << 16);
}

// ---------- prep: squared norms + fp32->bf16 copies (one block per row) ----------
__global__ __launch_bounds__(256) void prep_kernel(const float* __restrict__ S,
                                                   const float* __restrict__ T,
                                                   unsigned short* __restrict__ S16,
                                                   unsigned short* __restrict__ T16,
                                                   float* __restrict__ s2,
                                                   float* __restrict__ t2) {
    int rid = blockIdx.x;
    int t = threadIdx.x;
    const float* src;
    unsigned short* dst;
    float* nrm;
    if (rid < BB * LL) {
        src = S + (size_t)rid * DD; dst = S16 + (size_t)rid * DD; nrm = s2 + rid;
    } else {
        int r2 = rid - BB * LL;
        src = T + (size_t)r2 * DD; dst = T16 + (size_t)r2 * DD; nrm = t2 + r2;
    }
    float4 v = ((const float4*)src)[t];
    float s = v.x * v.x + v.y * v.y + v.z * v.z + v.w * v.w;
    ushort4 h;
    h.x = f2bf(v.x); h.y = f2bf(v.y); h.z = f2bf(v.z); h.w = f2bf(v.w);
    ((ushort4*)dst)[t] = h;
    #pragma unroll
    for (int off = 32; off; off >>= 1) s += __shfl_down(s, off, 64);
    __shared__ float red[4];
    if ((t & 63) == 0) red[t >> 6] = s;
    __syncthreads();
    if (t == 0) *nrm = red[0] + red[1] + red[2] + red[3];
}

// ---------- sqnorm only (fallback path) ----------
__global__ __launch_bounds__(256) void sqnorm_kernel(const float* __restrict__ x,
                                                     float* __restrict__ out) {
    int row = blockIdx.x;
    const float* p = x + (size_t)row * DD;
    int t = threadIdx.x;
    float4 v = ((const float4*)p)[t];
    float s = v.x * v.x + v.y * v.y + v.z * v.z + v.w * v.w;
    #pragma unroll
    for (int off = 32; off; off >>= 1) s += __shfl_down(s, off, 64);
    __shared__ float red[4];
    if ((t & 63) == 0) red[t >> 6] = s;
    __syncthreads();
    if (t == 0) out[row] = red[0] + red[1] + red[2] + red[3];
}

// ---------- MFMA bf16 distance GEMM: 128x128 tile, BK=32, 4 waves ----------
// Epilogue stores bf16 dist * LOG2E in diag-major layout [b][i+j][j], 512-diag stride.
__global__ __launch_bounds__(256) void distmf_kernel(const unsigned short* __restrict__ S16,
                                                     const unsigned short* __restrict__ T16,
                                                     const float* __restrict__ s2,
                                                     const float* __restrict__ t2,
                                                     unsigned short* __restrict__ Dd) {
    __shared__ unsigned short lds[2][2][128 * BK];   // [buf][A/B], 32 KB
    const int b    = blockIdx.y;
    const int tile = blockIdx.x;
    const int i0 = (tile & 1) * 128;
    const int j0 = (tile >> 1) * 128;
    const int tid = threadIdx.x, w = tid >> 6, lane = tid & 63;
    const int wr = w >> 1, wc = w & 1;

    const unsigned short* Sg = S16 + ((size_t)b * LL + i0) * DD;
    const unsigned short* Tg = T16 + ((size_t)b * LL + j0) * DD;

    const int sr   = w * 16 + (lane >> 2);
    const int skb0 = lane & 3;

    float4v acc[4][4];
    const float4v fzero = {0.f, 0.f, 0.f, 0.f};
    #pragma unroll
    for (int mi = 0; mi < 4; ++mi)
        #pragma unroll
        for (int ni = 0; ni < 4; ++ni) acc[mi][ni] = fzero;

    auto stage = [&](int buf, int k0) {
        #pragma unroll
        for (int n = 0; n < 2; ++n) {
            int r  = n * 64 + sr;
            int kb = skb0 ^ (r & 3);          // pre-swizzled GLOBAL source (LDS stays linear)
            __builtin_amdgcn_global_load_lds(
                (const __attribute__((address_space(1))) void*)(Sg + (size_t)r * DD + k0 + kb * 8),
                (__attribute__((address_space(3))) void*)(&lds[buf][0][(n * 64 + w * 16) * BK]),
                16, 0, 0);
            __builtin_amdgcn_global_load_lds(
                (const __attribute__((address_space(1))) void*)(Tg + (size_t)r * DD + k0 + kb * 8),
                (__attribute__((address_space(3))) void*)(&lds[buf][1][(n * 64 + w * 16) * BK]),
                16, 0, 0);
        }
    };

    stage(0, 0);
    for (int kt = 0; kt < 32; ++kt) {
        int cur = kt & 1;
        __syncthreads();
        if (kt < 31) stage(cur ^ 1, (kt + 1) * BK);

        const unsigned short* LA = &lds[cur][0][0];
        const unsigned short* LB = &lds[cur][1][0];
        short8v af[4], bf[4];
        #pragma unroll
        for (int mi = 0; mi < 4; ++mi) {
            int row = wr * 64 + mi * 16 + (lane & 15);
            int kb  = (lane >> 4) ^ (row & 3);
            af[mi] = *(const short8v*)(LA + row * BK + kb * 8);
        }
        #pragma unroll
        for (int ni = 0; ni < 4; ++ni) {
            int row = wc * 64 + ni * 16 + (lane & 15);
            int kb  = (lane >> 4) ^ (row & 3);
            bf[ni] = *(const short8v*)(LB + row * BK + kb * 8);
        }
        #pragma unroll
        for (int mi = 0; mi < 4; ++mi)
            #pragma unroll
            for (int ni = 0; ni < 4; ++ni)
                acc[mi][ni] = __builtin_amdgcn_mfma_f32_16x16x32_bf16(af[mi], bf[ni],
                                                                      acc[mi][ni], 0, 0, 0);
    }

    const int r0 = (lane >> 4) * 4;
    const int cf = lane & 15;
    unsigned short* Db = Dd + (size_t)b * NDPAD * 256;
    #pragma unroll
    for (int mi = 0; mi < 4; ++mi) {
        #pragma unroll
        for (int ni = 0; ni < 4; ++ni) {
            int j = j0 + wc * 64 + ni * 16 + cf;
            float tj = t2[b * LL + j];
            #pragma unroll
            for (int rg = 0; rg < 4; ++rg) {
                int i = i0 + wr * 64 + mi * 16 + r0 + rg;
                float sq = s2[b * LL + i] + tj - 2.0f * acc[mi][ni][rg];
                float dv = sqrtf(fmaxf(sq, 1e-12f));
                Db[(size_t)(i + j) * 256 + j] = f2bf(dv * LOG2E);
            }
        }
    }
}

// ---------- fp32 tiled distance GEMM (fallback if ws too small) ----------
__global__ __launch_bounds__(256) void dist_kernel(const float* __restrict__ S,
                                                   const float* __restrict__ T,
                                                   const float* __restrict__ s2,
                                                   const float* __restrict__ t2,
                                                   unsigned short* __restrict__ Dd) {
    int b  = blockIdx.z;
    int i0 = blockIdx.y * 64;
    int j0 = blockIdx.x * 64;
    const float* Sb = S + (size_t)b * LL * DD;
    const float* Tb = T + (size_t)b * LL * DD;
    __shared__ float sA[16][65];
    __shared__ float sB[16][65];
    int tid = threadIdx.x;
    int tx = tid & 15, ty = tid >> 4, lk = tid & 15, lm = tid >> 4;
    float acc[4][4] = {};
    for (int k0 = 0; k0 < DD; k0 += 16) {
        #pragma unroll
        for (int r = 0; r < 4; ++r) {
            int m = lm + 16 * r;
            sA[lk][m] = Sb[(size_t)(i0 + m) * DD + k0 + lk];
            sB[lk][m] = Tb[(size_t)(j0 + m) * DD + k0 + lk];
        }
        __syncthreads();
        #pragma unroll
        for (int kk = 0; kk < 16; ++kk) {
            float a[4], bv[4];
            #pragma unroll
            for (int ii = 0; ii < 4; ++ii) a[ii] = sA[kk][ty * 4 + ii];
            #pragma unroll
            for (int jj = 0; jj < 4; ++jj) bv[jj] = sB[kk][tx * 4 + jj];
            #pragma unroll
            for (int ii = 0; ii < 4; ++ii)
                #pragma unroll
                for (int jj = 0; jj < 4; ++jj)
                    acc[ii][jj] += a[ii] * bv[jj];
        }
        __syncthreads();
    }
    #pragma unroll
    for (int ii = 0; ii < 4; ++ii) {
        int p = i0 + ty * 4 + ii;
        float si = s2[b * LL + p];
        #pragma unroll
        for (int jj = 0; jj < 4; ++jj) {
            int q = j0 + tx * 4 + jj;
            float sq = si + t2[b * LL + q] - 2.0f * acc[ii][jj];
            float dv = sqrtf(fmaxf(sq, 1e-12f));
            Dd[((size_t)b * NDPAD + (p + q)) * 256 + q] = f2bf(dv * LOG2E);
        }
    }
}

// ---------- soft-DTW DP: one wave64 per batch, LDS-pipelined dist stream ----------
// Base-2 domain: dist was pre-scaled by log2(e); result scaled back by ln2.

// lane i <- lane i-1 via DPP wave_shr:1; lane 0 <- fill (old value, bound_ctrl=0)
__device__ __forceinline__ float wshr1(float src, float fill) {
    return __int_as_float(__builtin_amdgcn_update_dpp(
        __float_as_int(fill), __float_as_int(src), 0x138, 0xF, 0xF, false));
}

// softmin cell, 3 TRANS: m=min3 -> one exp2 term is exactly 1.
// s = 1 + 2^(m-med) + 2^(m-max); r = d + m - log2(s).
__device__ __forceinline__ float sdtw_cell3(bool valid, float dval, float a, float u, float l) {
    float m   = fminf(a, fminf(u, l));                       // v_min3
    float mid = __builtin_amdgcn_fmed3f(a, u, l);            // v_med3
    float M   = fmaxf(a, fmaxf(u, l));                       // v_max3
    float s   = (__builtin_amdgcn_exp2f(m - mid) + __builtin_amdgcn_exp2f(m - M)) + 1.0f;
    float r   = dval + m - __builtin_amdgcn_logf(s);
    return valid ? r : INFINITY;
}

__global__ __launch_bounds__(64) void sdtw_kernel(const unsigned short* __restrict__ Dg,
                                                  float* __restrict__ res) {
    __shared__ unsigned short sd[4][16 * 256];   // 4 chunk buffers x 8 KB = 32 KB
    const int b = blockIdx.x;
    const int lane = threadIdx.x;
    const float INF = INFINITY;
    const unsigned short* Db = Dg + (size_t)b * NDPAD * 256;

    auto prefetch = [&](int c) {
        #pragma unroll
        for (int q = 0; q < 8; ++q) {
            __builtin_amdgcn_global_load_lds(
                (const __attribute__((address_space(1))) void*)(Db + (size_t)c * 4096 + q * 512 + lane * 8),
                (__attribute__((address_space(3))) void*)(&sd[c & 3][q * 512]),
                16, 0, 0);
        }
    };

    prefetch(0);
    prefetch(1);

    float rm1_0 = INF, rm1_1 = INF, rm1_2 = INF, rm1_3 = INF;
    float rm2_0 = INF, rm2_1 = INF, rm2_2 = INF, rm2_3 = INF;
    float p2carry = (lane == 0) ? 0.0f : INF;    // p2(d) = p1(d-1); seed for d=2
    const int jb = 4 * lane + 1;

    for (int c = 0; c < 32; ++c) {
        if (c < 30) {
            prefetch(c + 2);                                  // 24 in flight
            asm volatile("s_waitcnt vmcnt(16)" ::: "memory"); // chunk c landed
        } else if (c == 30) {
            asm volatile("s_waitcnt vmcnt(8)" ::: "memory");
        } else {
            asm volatile("s_waitcnt vmcnt(0)" ::: "memory");
        }
        __builtin_amdgcn_sched_barrier(0);

        const unsigned short* Lp = &sd[c & 3][0];
        ushort4 pkts[16];
        #pragma unroll
        for (int q = 0; q < 16; ++q)
            pkts[q] = *(const ushort4*)(Lp + q * 256 + 4 * lane);

        const int vbase = 16 * c + 1 - jb;       // i-1 for slot0 at q=0
        #pragma unroll
        for (int q = 0; q < 16; ++q) {
            float p1 = wshr1(rm1_3, INF);        // DPP wave_shr:1, lane0=INF
            float p2 = p2carry;
            p2carry = p1;
            float d0 = bf2f(pkts[q].x), d1 = bf2f(pkts[q].y);
            float d2v = bf2f(pkts[q].z), d3 = bf2f(pkts[q].w);
            float rc0 = sdtw_cell3((unsigned)(vbase + q)     < 256u, d0,  p2,    rm1_0, p1);
            float rc1 = sdtw_cell3((unsigned)(vbase + q - 1) < 256u, d1,  rm2_0, rm1_1, rm1_0);
            float rc2 = sdtw_cell3((unsigned)(vbase + q - 2) < 256u, d2v, rm2_1, rm1_2, rm1_1);
            float rc3 = sdtw_cell3((unsigned)(vbase + q - 3) < 256u, d3,  rm2_2, rm1_3, rm1_2);
            rm2_0 = rm1_0; rm2_1 = rm1_1; rm2_2 = rm1_2; rm2_3 = rm1_3;
            rm1_0 = rc0;  rm1_1 = rc1;  rm1_2 = rc2;  rm1_3 = rc3;
        }
    }
    // last real diagonal d=512 sits in rm2 after the dummy d=513 step
    if (lane == 63) res[b] = rm2_3 * LN2;
}

// ---------- final mean over batches ----------
__global__ void reduce_kernel(const float* __restrict__ res, float* __restrict__ out) {
    int t = threadIdx.x;
    float v = res[t];
    #pragma unroll
    for (int off = 32; off; off >>= 1) v += __shfl_down(v, off, 64);
    if (t == 0) out[0] = v * (1.0f / BB);
}

extern "C" void kernel_launch(void* const* d_in, const int* in_sizes, int n_in,
                              void* d_out, int out_size, void* d_ws, size_t ws_size,
                              hipStream_t stream) {
    const float* S = (const float*)d_in[0];
    const float* T = (const float*)d_in[1];

    const size_t nElem  = (size_t)BB * LL * DD;                 // 16,777,216
    const size_t nDiag  = (size_t)BB * NDPAD * 256;             // 8,388,608 ushorts
    const size_t needBF = nElem * 2 * sizeof(unsigned short)
                        + nDiag * sizeof(unsigned short)
                        + ((size_t)2 * BB * LL + BB) * sizeof(float);

    if (ws_size >= needBF) {
        unsigned short* diag = (unsigned short*)d_ws;
        unsigned short* S16  = diag + nDiag;
        unsigned short* T16  = S16 + nElem;
        float* s2  = (float*)(T16 + nElem);
        float* t2  = s2 + BB * LL;
        float* rsv = t2 + BB * LL;

        prep_kernel<<<2 * BB * LL, 256, 0, stream>>>(S, T, S16, T16, s2, t2);
        distmf_kernel<<<dim3(4, BB), 256, 0, stream>>>(S16, T16, s2, t2, diag);
        sdtw_kernel<<<BB, 64, 0, stream>>>(diag, rsv);
        reduce_kernel<<<1, 64, 0, stream>>>(rsv, (float*)d_out);
    } else {
        unsigned short* diag = (unsigned short*)d_ws;
        float* s2  = (float*)(diag + nDiag);
        float* t2  = s2 + BB * LL;
        float* rsv = t2 + BB * LL;

        sqnorm_kernel<<<BB * LL, 256, 0, stream>>>(S, s2);
        sqnorm_kernel<<<BB * LL, 256, 0, stream>>>(T, t2);
        dim3 g(LL / 64, LL / 64, BB);
        dist_kernel<<<g, 256, 0, stream>>>(S, T, s2, t2, diag);
        sdtw_kernel<<<BB, 64, 0, stream>>>(diag, rsv);
        reduce_kernel<<<1, 64, 0, stream>>>(rsv, (float*)d_out);
    }
}

// Round 6
// 102.871 us; speedup vs baseline: 2.2233x; 1.3787x over previous
//
#include <hip/hip_runtime.h>
#include <math.h>

#define BB 64
#define LL 256
#define DD 1024
#define NDPAD 512   // padded anti-diagonal count per batch (511 real + 1 pad)
#define BK 32
#define LOG2E 1.4426950408889634f
#define LN2   0.6931471805599453f

typedef __attribute__((ext_vector_type(8))) short short8v;
typedef __attribute__((ext_vector_type(4))) float float4v;

__device__ __forceinline__ unsigned short f2bf(float f) {
    unsigned u = __float_as_uint(f);
    unsigned r = (u + 0x7fffu + ((u >> 16) & 1u)) >> 16;   // RNE
    return (unsigned short)r;
}
__device__ __forceinline__ float bf2f(unsigned short u) {
    return __uint_as_float(((unsigned)u) << 16);
}

// ---------- prep: squared norms + fp32->bf16 copies (one block per row) ----------
__global__ __launch_bounds__(256) void prep_kernel(const float* __restrict__ S,
                                                   const float* __restrict__ T,
                                                   unsigned short* __restrict__ S16,
                                                   unsigned short* __restrict__ T16,
                                                   float* __restrict__ s2,
                                                   float* __restrict__ t2) {
    int rid = blockIdx.x;
    int t = threadIdx.x;
    const float* src;
    unsigned short* dst;
    float* nrm;
    if (rid < BB * LL) {
        src = S + (size_t)rid * DD; dst = S16 + (size_t)rid * DD; nrm = s2 + rid;
    } else {
        int r2 = rid - BB * LL;
        src = T + (size_t)r2 * DD; dst = T16 + (size_t)r2 * DD; nrm = t2 + r2;
    }
    float4 v = ((const float4*)src)[t];
    float s = v.x * v.x + v.y * v.y + v.z * v.z + v.w * v.w;
    ushort4 h;
    h.x = f2bf(v.x); h.y = f2bf(v.y); h.z = f2bf(v.z); h.w = f2bf(v.w);
    ((ushort4*)dst)[t] = h;
    #pragma unroll
    for (int off = 32; off; off >>= 1) s += __shfl_down(s, off, 64);
    __shared__ float red[4];
    if ((t & 63) == 0) red[t >> 6] = s;
    __syncthreads();
    if (t == 0) *nrm = red[0] + red[1] + red[2] + red[3];
}

// ---------- sqnorm only (fallback path) ----------
__global__ __launch_bounds__(256) void sqnorm_kernel(const float* __restrict__ x,
                                                     float* __restrict__ out) {
    int row = blockIdx.x;
    const float* p = x + (size_t)row * DD;
    int t = threadIdx.x;
    float4 v = ((const float4*)p)[t];
    float s = v.x * v.x + v.y * v.y + v.z * v.z + v.w * v.w;
    #pragma unroll
    for (int off = 32; off; off >>= 1) s += __shfl_down(s, off, 64);
    __shared__ float red[4];
    if ((t & 63) == 0) red[t >> 6] = s;
    __syncthreads();
    if (t == 0) out[row] = red[0] + red[1] + red[2] + red[3];
}

// ---------- MFMA bf16 distance GEMM: 128x128 tile, BK=32, 4 waves ----------
// Epilogue stores bf16 dist * LOG2E in diag-major layout [b][i+j][j], 512-diag stride.
__global__ __launch_bounds__(256) void distmf_kernel(const unsigned short* __restrict__ S16,
                                                     const unsigned short* __restrict__ T16,
                                                     const float* __restrict__ s2,
                                                     const float* __restrict__ t2,
                                                     unsigned short* __restrict__ Dd) {
    __shared__ unsigned short lds[2][2][128 * BK];   // [buf][A/B], 32 KB
    const int b    = blockIdx.y;
    const int tile = blockIdx.x;
    const int i0 = (tile & 1) * 128;
    const int j0 = (tile >> 1) * 128;
    const int tid = threadIdx.x, w = tid >> 6, lane = tid & 63;
    const int wr = w >> 1, wc = w & 1;

    const unsigned short* Sg = S16 + ((size_t)b * LL + i0) * DD;
    const unsigned short* Tg = T16 + ((size_t)b * LL + j0) * DD;

    const int sr   = w * 16 + (lane >> 2);
    const int skb0 = lane & 3;

    float4v acc[4][4];
    const float4v fzero = {0.f, 0.f, 0.f, 0.f};
    #pragma unroll
    for (int mi = 0; mi < 4; ++mi)
        #pragma unroll
        for (int ni = 0; ni < 4; ++ni) acc[mi][ni] = fzero;

    auto stage = [&](int buf, int k0) {
        #pragma unroll
        for (int n = 0; n < 2; ++n) {
            int r  = n * 64 + sr;
            int kb = skb0 ^ (r & 3);          // pre-swizzled GLOBAL source (LDS stays linear)
            __builtin_amdgcn_global_load_lds(
                (const __attribute__((address_space(1))) void*)(Sg + (size_t)r * DD + k0 + kb * 8),
                (__attribute__((address_space(3))) void*)(&lds[buf][0][(n * 64 + w * 16) * BK]),
                16, 0, 0);
            __builtin_amdgcn_global_load_lds(
                (const __attribute__((address_space(1))) void*)(Tg + (size_t)r * DD + k0 + kb * 8),
                (__attribute__((address_space(3))) void*)(&lds[buf][1][(n * 64 + w * 16) * BK]),
                16, 0, 0);
        }
    };

    stage(0, 0);
    for (int kt = 0; kt < 32; ++kt) {
        int cur = kt & 1;
        __syncthreads();
        if (kt < 31) stage(cur ^ 1, (kt + 1) * BK);

        const unsigned short* LA = &lds[cur][0][0];
        const unsigned short* LB = &lds[cur][1][0];
        short8v af[4], bf[4];
        #pragma unroll
        for (int mi = 0; mi < 4; ++mi) {
            int row = wr * 64 + mi * 16 + (lane & 15);
            int kb  = (lane >> 4) ^ (row & 3);
            af[mi] = *(const short8v*)(LA + row * BK + kb * 8);
        }
        #pragma unroll
        for (int ni = 0; ni < 4; ++ni) {
            int row = wc * 64 + ni * 16 + (lane & 15);
            int kb  = (lane >> 4) ^ (row & 3);
            bf[ni] = *(const short8v*)(LB + row * BK + kb * 8);
        }
        #pragma unroll
        for (int mi = 0; mi < 4; ++mi)
            #pragma unroll
            for (int ni = 0; ni < 4; ++ni)
                acc[mi][ni] = __builtin_amdgcn_mfma_f32_16x16x32_bf16(af[mi], bf[ni],
                                                                      acc[mi][ni], 0, 0, 0);
    }

    const int r0 = (lane >> 4) * 4;
    const int cf = lane & 15;
    unsigned short* Db = Dd + (size_t)b * NDPAD * 256;
    #pragma unroll
    for (int mi = 0; mi < 4; ++mi) {
        #pragma unroll
        for (int ni = 0; ni < 4; ++ni) {
            int j = j0 + wc * 64 + ni * 16 + cf;
            float tj = t2[b * LL + j];
            #pragma unroll
            for (int rg = 0; rg < 4; ++rg) {
                int i = i0 + wr * 64 + mi * 16 + r0 + rg;
                float sq = s2[b * LL + i] + tj - 2.0f * acc[mi][ni][rg];
                float dv = sqrtf(fmaxf(sq, 1e-12f));
                Db[(size_t)(i + j) * 256 + j] = f2bf(dv * LOG2E);
            }
        }
    }
}

// ---------- fp32 tiled distance GEMM (fallback if ws too small) ----------
__global__ __launch_bounds__(256) void dist_kernel(const float* __restrict__ S,
                                                   const float* __restrict__ T,
                                                   const float* __restrict__ s2,
                                                   const float* __restrict__ t2,
                                                   unsigned short* __restrict__ Dd) {
    int b  = blockIdx.z;
    int i0 = blockIdx.y * 64;
    int j0 = blockIdx.x * 64;
    const float* Sb = S + (size_t)b * LL * DD;
    const float* Tb = T + (size_t)b * LL * DD;
    __shared__ float sA[16][65];
    __shared__ float sB[16][65];
    int tid = threadIdx.x;
    int tx = tid & 15, ty = tid >> 4, lk = tid & 15, lm = tid >> 4;
    float acc[4][4] = {};
    for (int k0 = 0; k0 < DD; k0 += 16) {
        #pragma unroll
        for (int r = 0; r < 4; ++r) {
            int m = lm + 16 * r;
            sA[lk][m] = Sb[(size_t)(i0 + m) * DD + k0 + lk];
            sB[lk][m] = Tb[(size_t)(j0 + m) * DD + k0 + lk];
        }
        __syncthreads();
        #pragma unroll
        for (int kk = 0; kk < 16; ++kk) {
            float a[4], bv[4];
            #pragma unroll
            for (int ii = 0; ii < 4; ++ii) a[ii] = sA[kk][ty * 4 + ii];
            #pragma unroll
            for (int jj = 0; jj < 4; ++jj) bv[jj] = sB[kk][tx * 4 + jj];
            #pragma unroll
            for (int ii = 0; ii < 4; ++ii)
                #pragma unroll
                for (int jj = 0; jj < 4; ++jj)
                    acc[ii][jj] += a[ii] * bv[jj];
        }
        __syncthreads();
    }
    #pragma unroll
    for (int ii = 0; ii < 4; ++ii) {
        int p = i0 + ty * 4 + ii;
        float si = s2[b * LL + p];
        #pragma unroll
        for (int jj = 0; jj < 4; ++jj) {
            int q = j0 + tx * 4 + jj;
            float sq = si + t2[b * LL + q] - 2.0f * acc[ii][jj];
            float dv = sqrtf(fmaxf(sq, 1e-12f));
            Dd[((size_t)b * NDPAD + (p + q)) * 256 + q] = f2bf(dv * LOG2E);
        }
    }
}

// ---------- soft-DTW DP: 4 waves per batch, chunk-skewed wavefront ----------
// Wave w owns cols 64w+1..64w+64 (1 cell/lane). Wave w processes 16-diagonal
// chunk c during round r=c+w; boundary col values flow w -> w+1 via LDS with a
// one-round skew, so sync is ONE barrier per 16 steps.

// lane i <- lane i-1 via DPP wave_shr:1; lane 0 <- fill (old value, bound_ctrl=0)
__device__ __forceinline__ float wshr1(float src, float fill) {
    return __int_as_float(__builtin_amdgcn_update_dpp(
        __float_as_int(fill), __float_as_int(src), 0x138, 0xF, 0xF, false));
}

__global__ __launch_bounds__(256) void sdtw_kernel(const unsigned short* __restrict__ Dg,
                                                   float* __restrict__ res) {
    __shared__ unsigned short sd[8][16 * 256];   // 8 chunk buffers x 8 KB = 64 KB
    __shared__ float bbuf[3][2][16];             // boundary rings (writer waves 0..2)
    const int b = blockIdx.x;
    const int tid = threadIdx.x;
    const int w = tid >> 6;                      // wave 0..3
    const int lane = tid & 63;
    const float INF = INFINITY;
    const unsigned short* Db = Dg + (size_t)b * NDPAD * 256;

    auto prefetch = [&](int c) {
        #pragma unroll
        for (int q = 0; q < 8; ++q) {
            __builtin_amdgcn_global_load_lds(
                (const __attribute__((address_space(1))) void*)(Db + (size_t)c * 4096 + q * 512 + lane * 8),
                (__attribute__((address_space(3))) void*)(&sd[c & 7][q * 512]),
                16, 0, 0);
        }
    };

    const int col0 = 64 * w + lane;              // 0-based column (j-1)
    float rm1 = INF, rm2 = INF;
    float p2carry = (tid == 0) ? 0.0f : INF;     // R(0,0) seed for wave0 lane0
    float bcarry = INF;

    if (w == 0) {
        prefetch(0);
        prefetch(1);
        asm volatile("s_waitcnt vmcnt(8)" ::: "memory");   // chunk 0 landed
    }
    asm volatile("s_waitcnt lgkmcnt(0)" ::: "memory");
    __builtin_amdgcn_s_barrier();

    for (int r = 0; r < 35; ++r) {
        if (w == 0 && r + 2 < 32) prefetch(r + 2);
        const int c = r - w;
        if (0 <= c && c < 32) {
            const unsigned short* Lp = &sd[c & 7][0];
            float dv[16];
            #pragma unroll
            for (int q = 0; q < 16; ++q)
                dv[q] = bf2f(Lp[q * 256 + col0]);

            float bv[16];
            if (w == 0) {
                #pragma unroll
                for (int q = 0; q < 16; ++q) bv[q] = INF;
            } else {
                const float4* bp4 = (const float4*)&bbuf[w - 1][c & 1][0];
                float4 b0 = bp4[0], b1 = bp4[1], b2 = bp4[2], b3 = bp4[3];
                bv[0] = bcarry;
                bv[1] = b0.x;  bv[2] = b0.y;  bv[3] = b0.z;  bv[4] = b0.w;
                bv[5] = b1.x;  bv[6] = b1.y;  bv[7] = b1.z;  bv[8] = b1.w;
                bv[9] = b2.x;  bv[10] = b2.y; bv[11] = b2.z; bv[12] = b2.w;
                bv[13] = b3.x; bv[14] = b3.y; bv[15] = b3.z;
                bcarry = b3.w;
            }
            asm volatile("s_waitcnt lgkmcnt(0)" ::: "memory");
            __builtin_amdgcn_sched_barrier(0);

            const int ibase = 16 * c - col0;     // (i-1) at q=0
            float bb[16];
            #pragma unroll
            for (int q = 0; q < 16; ++q) {
                float p1 = wshr1(rm1, bv[q]);    // left neighbor's diag d-1
                float p2 = p2carry;              // left neighbor's diag d-2
                p2carry = p1;
                float m   = fminf(p2, fminf(rm1, p1));
                float mid = __builtin_amdgcn_fmed3f(p2, rm1, p1);
                float M   = fmaxf(p2, fmaxf(rm1, p1));
                float s   = (__builtin_amdgcn_exp2f(m - mid) +
                             __builtin_amdgcn_exp2f(m - M)) + 1.0f;
                float rcv = dv[q] + m - __builtin_amdgcn_logf(s);
                bool valid = (unsigned)(ibase + q) < 256u;
                rcv = valid ? rcv : INF;
                rm2 = rm1;
                rm1 = rcv;
                bb[q] = rcv;
            }
            if (w < 3 && lane == 63) {           // publish 16 boundary values
                float4* op = (float4*)&bbuf[w][c & 1][0];
                op[0] = make_float4(bb[0], bb[1], bb[2], bb[3]);
                op[1] = make_float4(bb[4], bb[5], bb[6], bb[7]);
                op[2] = make_float4(bb[8], bb[9], bb[10], bb[11]);
                op[3] = make_float4(bb[12], bb[13], bb[14], bb[15]);
            }
        }
        if (w == 0) {
            if (r < 30) asm volatile("s_waitcnt vmcnt(8)" ::: "memory");
            else        asm volatile("s_waitcnt vmcnt(0)" ::: "memory");
        }
        asm volatile("s_waitcnt lgkmcnt(0)" ::: "memory");
        __builtin_amdgcn_s_barrier();
    }
    // After dummy step d=513, rm2 of wave3 lane63 = R(256,256)
    if (tid == 255) res[b] = rm2 * LN2;
}

// ---------- final mean over batches ----------
__global__ void reduce_kernel(const float* __restrict__ res, float* __restrict__ out) {
    int t = threadIdx.x;
    float v = res[t];
    #pragma unroll
    for (int off = 32; off; off >>= 1) v += __shfl_down(v, off, 64);
    if (t == 0) out[0] = v * (1.0f / BB);
}

extern "C" void kernel_launch(void* const* d_in, const int* in_sizes, int n_in,
                              void* d_out, int out_size, void* d_ws, size_t ws_size,
                              hipStream_t stream) {
    const float* S = (const float*)d_in[0];
    const float* T = (const float*)d_in[1];

    const size_t nElem  = (size_t)BB * LL * DD;                 // 16,777,216
    const size_t nDiag  = (size_t)BB * NDPAD * 256;             // 8,388,608 ushorts
    const size_t needBF = nElem * 2 * sizeof(unsigned short)
                        + nDiag * sizeof(unsigned short)
                        + ((size_t)2 * BB * LL + BB) * sizeof(float);

    if (ws_size >= needBF) {
        unsigned short* diag = (unsigned short*)d_ws;
        unsigned short* S16  = diag + nDiag;
        unsigned short* T16  = S16 + nElem;
        float* s2  = (float*)(T16 + nElem);
        float* t2  = s2 + BB * LL;
        float* rsv = t2 + BB * LL;

        prep_kernel<<<2 * BB * LL, 256, 0, stream>>>(S, T, S16, T16, s2, t2);
        distmf_kernel<<<dim3(4, BB), 256, 0, stream>>>(S16, T16, s2, t2, diag);
        sdtw_kernel<<<BB, 256, 0, stream>>>(diag, rsv);
        reduce_kernel<<<1, 64, 0, stream>>>(rsv, (float*)d_out);
    } else {
        unsigned short* diag = (unsigned short*)d_ws;
        float* s2  = (float*)(diag + nDiag);
        float* t2  = s2 + BB * LL;
        float* rsv = t2 + BB * LL;

        sqnorm_kernel<<<BB * LL, 256, 0, stream>>>(S, s2);
        sqnorm_kernel<<<BB * LL, 256, 0, stream>>>(T, t2);
        dim3 g(LL / 64, LL / 64, BB);
        dist_kernel<<<g, 256, 0, stream>>>(S, T, s2, t2, diag);
        sdtw_kernel<<<BB, 256, 0, stream>>>(diag, rsv);
        reduce_kernel<<<1, 64, 0, stream>>>(rsv, (float*)d_out);
    }
}

// Round 7
// 99.276 us; speedup vs baseline: 2.3038x; 1.0362x over previous
//
#include <hip/hip_runtime.h>
#include <math.h>

#define BB 64
#define LL 256
#define DD 1024
#define NDPAD 512   // padded anti-diagonal count per batch (511 real + 1 pad)
#define BK 32
#define LOG2E 1.4426950408889634f
#define LN2   0.6931471805599453f

typedef __attribute__((ext_vector_type(8))) short short8v;
typedef __attribute__((ext_vector_type(4))) float float4v;

__device__ __forceinline__ unsigned short f2bf(float f) {
    unsigned u = __float_as_uint(f);
    unsigned r = (u + 0x7fffu + ((u >> 16) & 1u)) >> 16;   // RNE
    return (unsigned short)r;
}
__device__ __forceinline__ float bf2f(unsigned short u) {
    return __uint_as_float(((unsigned)u) << 16);
}

// ---------- prep: one WAVE per row — stream fp32->bf16 + row norm, no LDS/sync ----------
__global__ __launch_bounds__(256) void prep_kernel(const float* __restrict__ S,
                                                   const float* __restrict__ T,
                                                   unsigned short* __restrict__ S16,
                                                   unsigned short* __restrict__ T16,
                                                   float* __restrict__ s2,
                                                   float* __restrict__ t2) {
    int wid  = (blockIdx.x * 256 + threadIdx.x) >> 6;   // global wave id = row id
    int lane = threadIdx.x & 63;

    const float* src;
    unsigned short* dst;
    float* nrm;
    if (wid < BB * LL) {
        src = S + (size_t)wid * DD; dst = S16 + (size_t)wid * DD; nrm = s2 + wid;
    } else {
        int r2 = wid - BB * LL;
        src = T + (size_t)r2 * DD; dst = T16 + (size_t)r2 * DD; nrm = t2 + r2;
    }

    float s = 0.0f;
    #pragma unroll
    for (int k = 0; k < 4; ++k) {
        float4 v = ((const float4*)src)[lane + 64 * k];
        s += v.x * v.x + v.y * v.y + v.z * v.z + v.w * v.w;
        ushort4 h;
        h.x = f2bf(v.x); h.y = f2bf(v.y); h.z = f2bf(v.z); h.w = f2bf(v.w);
        ((ushort4*)dst)[lane + 64 * k] = h;
    }
    #pragma unroll
    for (int off = 32; off; off >>= 1) s += __shfl_down(s, off, 64);
    if (lane == 0) *nrm = s;
}

// ---------- sqnorm only (fallback path) ----------
__global__ __launch_bounds__(256) void sqnorm_kernel(const float* __restrict__ x,
                                                     float* __restrict__ out) {
    int row = blockIdx.x;
    const float* p = x + (size_t)row * DD;
    int t = threadIdx.x;
    float4 v = ((const float4*)p)[t];
    float s = v.x * v.x + v.y * v.y + v.z * v.z + v.w * v.w;
    #pragma unroll
    for (int off = 32; off; off >>= 1) s += __shfl_down(s, off, 64);
    __shared__ float red[4];
    if ((t & 63) == 0) red[t >> 6] = s;
    __syncthreads();
    if (t == 0) out[row] = red[0] + red[1] + red[2] + red[3];
}

// ---------- MFMA bf16 distance GEMM: 128x128 tile, BK=32, 4 waves ----------
// grid (BB, 4): the 4 tiles of batch b have linear ids {b, b+64, b+128, b+192}
// -> same XCD under round-robin dispatch, so their identical S16/T16 fetches
// merge in that XCD's L2.
// Epilogue stores bf16 dist * LOG2E in diag-major layout [b][i+j][j], 512-diag stride.
__global__ __launch_bounds__(256) void distmf_kernel(const unsigned short* __restrict__ S16,
                                                     const unsigned short* __restrict__ T16,
                                                     const float* __restrict__ s2,
                                                     const float* __restrict__ t2,
                                                     unsigned short* __restrict__ Dd) {
    __shared__ unsigned short lds[2][2][128 * BK];   // [buf][A/B], 32 KB
    const int b    = blockIdx.x;
    const int tile = blockIdx.y;
    const int i0 = (tile & 1) * 128;
    const int j0 = (tile >> 1) * 128;
    const int tid = threadIdx.x, w = tid >> 6, lane = tid & 63;
    const int wr = w >> 1, wc = w & 1;

    const unsigned short* Sg = S16 + ((size_t)b * LL + i0) * DD;
    const unsigned short* Tg = T16 + ((size_t)b * LL + j0) * DD;

    const int sr   = w * 16 + (lane >> 2);
    const int skb0 = lane & 3;

    float4v acc[4][4];
    const float4v fzero = {0.f, 0.f, 0.f, 0.f};
    #pragma unroll
    for (int mi = 0; mi < 4; ++mi)
        #pragma unroll
        for (int ni = 0; ni < 4; ++ni) acc[mi][ni] = fzero;

    auto stage = [&](int buf, int k0) {
        #pragma unroll
        for (int n = 0; n < 2; ++n) {
            int r  = n * 64 + sr;
            int kb = skb0 ^ (r & 3);          // pre-swizzled GLOBAL source (LDS stays linear)
            __builtin_amdgcn_global_load_lds(
                (const __attribute__((address_space(1))) void*)(Sg + (size_t)r * DD + k0 + kb * 8),
                (__attribute__((address_space(3))) void*)(&lds[buf][0][(n * 64 + w * 16) * BK]),
                16, 0, 0);
            __builtin_amdgcn_global_load_lds(
                (const __attribute__((address_space(1))) void*)(Tg + (size_t)r * DD + k0 + kb * 8),
                (__attribute__((address_space(3))) void*)(&lds[buf][1][(n * 64 + w * 16) * BK]),
                16, 0, 0);
        }
    };

    stage(0, 0);
    for (int kt = 0; kt < 32; ++kt) {
        int cur = kt & 1;
        __syncthreads();
        if (kt < 31) stage(cur ^ 1, (kt + 1) * BK);

        const unsigned short* LA = &lds[cur][0][0];
        const unsigned short* LB = &lds[cur][1][0];
        short8v af[4], bf[4];
        #pragma unroll
        for (int mi = 0; mi < 4; ++mi) {
            int row = wr * 64 + mi * 16 + (lane & 15);
            int kb  = (lane >> 4) ^ (row & 3);
            af[mi] = *(const short8v*)(LA + row * BK + kb * 8);
        }
        #pragma unroll
        for (int ni = 0; ni < 4; ++ni) {
            int row = wc * 64 + ni * 16 + (lane & 15);
            int kb  = (lane >> 4) ^ (row & 3);
            bf[ni] = *(const short8v*)(LB + row * BK + kb * 8);
        }
        #pragma unroll
        for (int mi = 0; mi < 4; ++mi)
            #pragma unroll
            for (int ni = 0; ni < 4; ++ni)
                acc[mi][ni] = __builtin_amdgcn_mfma_f32_16x16x32_bf16(af[mi], bf[ni],
                                                                      acc[mi][ni], 0, 0, 0);
    }

    const int r0 = (lane >> 4) * 4;
    const int cf = lane & 15;
    unsigned short* Db = Dd + (size_t)b * NDPAD * 256;
    #pragma unroll
    for (int mi = 0; mi < 4; ++mi) {
        #pragma unroll
        for (int ni = 0; ni < 4; ++ni) {
            int j = j0 + wc * 64 + ni * 16 + cf;
            float tj = t2[b * LL + j];
            #pragma unroll
            for (int rg = 0; rg < 4; ++rg) {
                int i = i0 + wr * 64 + mi * 16 + r0 + rg;
                float sq = s2[b * LL + i] + tj - 2.0f * acc[mi][ni][rg];
                float dv = sqrtf(fmaxf(sq, 1e-12f));
                Db[(size_t)(i + j) * 256 + j] = f2bf(dv * LOG2E);
            }
        }
    }
}

// ---------- fp32 tiled distance GEMM (fallback if ws too small) ----------
__global__ __launch_bounds__(256) void dist_kernel(const float* __restrict__ S,
                                                   const float* __restrict__ T,
                                                   const float* __restrict__ s2,
                                                   const float* __restrict__ t2,
                                                   unsigned short* __restrict__ Dd) {
    int b  = blockIdx.z;
    int i0 = blockIdx.y * 64;
    int j0 = blockIdx.x * 64;
    const float* Sb = S + (size_t)b * LL * DD;
    const float* Tb = T + (size_t)b * LL * DD;
    __shared__ float sA[16][65];
    __shared__ float sB[16][65];
    int tid = threadIdx.x;
    int tx = tid & 15, ty = tid >> 4, lk = tid & 15, lm = tid >> 4;
    float acc[4][4] = {};
    for (int k0 = 0; k0 < DD; k0 += 16) {
        #pragma unroll
        for (int r = 0; r < 4; ++r) {
            int m = lm + 16 * r;
            sA[lk][m] = Sb[(size_t)(i0 + m) * DD + k0 + lk];
            sB[lk][m] = Tb[(size_t)(j0 + m) * DD + k0 + lk];
        }
        __syncthreads();
        #pragma unroll
        for (int kk = 0; kk < 16; ++kk) {
            float a[4], bv[4];
            #pragma unroll
            for (int ii = 0; ii < 4; ++ii) a[ii] = sA[kk][ty * 4 + ii];
            #pragma unroll
            for (int jj = 0; jj < 4; ++jj) bv[jj] = sB[kk][tx * 4 + jj];
            #pragma unroll
            for (int ii = 0; ii < 4; ++ii)
                #pragma unroll
                for (int jj = 0; jj < 4; ++jj)
                    acc[ii][jj] += a[ii] * bv[jj];
        }
        __syncthreads();
    }
    #pragma unroll
    for (int ii = 0; ii < 4; ++ii) {
        int p = i0 + ty * 4 + ii;
        float si = s2[b * LL + p];
        #pragma unroll
        for (int jj = 0; jj < 4; ++jj) {
            int q = j0 + tx * 4 + jj;
            float sq = si + t2[b * LL + q] - 2.0f * acc[ii][jj];
            float dv = sqrtf(fmaxf(sq, 1e-12f));
            Dd[((size_t)b * NDPAD + (p + q)) * 256 + q] = f2bf(dv * LOG2E);
        }
    }
}

// ---------- soft-DTW DP: 4 waves per batch, chunk-skewed wavefront ----------
// Wave w owns cols 64w+1..64w+64 (1 cell/lane). Wave w processes 16-diagonal
// chunk c during round r=c+w; boundary col values flow w -> w+1 via LDS with a
// one-round skew, so sync is ONE barrier per 16 steps.

// lane i <- lane i-1 via DPP wave_shr:1; lane 0 <- fill (old value, bound_ctrl=0)
__device__ __forceinline__ float wshr1(float src, float fill) {
    return __int_as_float(__builtin_amdgcn_update_dpp(
        __float_as_int(fill), __float_as_int(src), 0x138, 0xF, 0xF, false));
}

__global__ __launch_bounds__(256) void sdtw_kernel(const unsigned short* __restrict__ Dg,
                                                   float* __restrict__ res) {
    __shared__ unsigned short sd[8][16 * 256];   // 8 chunk buffers x 8 KB = 64 KB
    __shared__ float bbuf[3][2][16];             // boundary rings (writer waves 0..2)
    const int b = blockIdx.x;
    const int tid = threadIdx.x;
    const int w = tid >> 6;                      // wave 0..3
    const int lane = tid & 63;
    const float INF = INFINITY;
    const unsigned short* Db = Dg + (size_t)b * NDPAD * 256;

    auto prefetch = [&](int c) {
        #pragma unroll
        for (int q = 0; q < 8; ++q) {
            __builtin_amdgcn_global_load_lds(
                (const __attribute__((address_space(1))) void*)(Db + (size_t)c * 4096 + q * 512 + lane * 8),
                (__attribute__((address_space(3))) void*)(&sd[c & 7][q * 512]),
                16, 0, 0);
        }
    };

    const int col0 = 64 * w + lane;              // 0-based column (j-1)
    float rm1 = INF, rm2 = INF;
    float p2carry = (tid == 0) ? 0.0f : INF;     // R(0,0) seed for wave0 lane0
    float bcarry = INF;

    if (w == 0) {
        prefetch(0);
        prefetch(1);
        asm volatile("s_waitcnt vmcnt(8)" ::: "memory");   // chunk 0 landed
    }
    asm volatile("s_waitcnt lgkmcnt(0)" ::: "memory");
    __builtin_amdgcn_s_barrier();

    for (int r = 0; r < 35; ++r) {
        if (w == 0 && r + 2 < 32) prefetch(r + 2);
        const int c = r - w;
        if (0 <= c && c < 32) {
            const unsigned short* Lp = &sd[c & 7][0];
            float dv[16];
            #pragma unroll
            for (int q = 0; q < 16; ++q)
                dv[q] = bf2f(Lp[q * 256 + col0]);

            float bv[16];
            if (w == 0) {
                #pragma unroll
                for (int q = 0; q < 16; ++q) bv[q] = INF;
            } else {
                const float4* bp4 = (const float4*)&bbuf[w - 1][c & 1][0];
                float4 b0 = bp4[0], b1 = bp4[1], b2 = bp4[2], b3 = bp4[3];
                bv[0] = bcarry;
                bv[1] = b0.x;  bv[2] = b0.y;  bv[3] = b0.z;  bv[4] = b0.w;
                bv[5] = b1.x;  bv[6] = b1.y;  bv[7] = b1.z;  bv[8] = b1.w;
                bv[9] = b2.x;  bv[10] = b2.y; bv[11] = b2.z; bv[12] = b2.w;
                bv[13] = b3.x; bv[14] = b3.y; bv[15] = b3.z;
                bcarry = b3.w;
            }
            asm volatile("s_waitcnt lgkmcnt(0)" ::: "memory");
            __builtin_amdgcn_sched_barrier(0);

            const int ibase = 16 * c - col0;     // (i-1) at q=0
            float bb[16];
            #pragma unroll
            for (int q = 0; q < 16; ++q) {
                float p1 = wshr1(rm1, bv[q]);    // left neighbor's diag d-1
                float p2 = p2carry;              // left neighbor's diag d-2
                p2carry = p1;
                float m   = fminf(p2, fminf(rm1, p1));
                float mid = __builtin_amdgcn_fmed3f(p2, rm1, p1);
                float M   = fmaxf(p2, fmaxf(rm1, p1));
                float s   = (__builtin_amdgcn_exp2f(m - mid) +
                             __builtin_amdgcn_exp2f(m - M)) + 1.0f;
                float rcv = dv[q] + m - __builtin_amdgcn_logf(s);
                bool valid = (unsigned)(ibase + q) < 256u;
                rcv = valid ? rcv : INF;
                rm2 = rm1;
                rm1 = rcv;
                bb[q] = rcv;
            }
            if (w < 3 && lane == 63) {           // publish 16 boundary values
                float4* op = (float4*)&bbuf[w][c & 1][0];
                op[0] = make_float4(bb[0], bb[1], bb[2], bb[3]);
                op[1] = make_float4(bb[4], bb[5], bb[6], bb[7]);
                op[2] = make_float4(bb[8], bb[9], bb[10], bb[11]);
                op[3] = make_float4(bb[12], bb[13], bb[14], bb[15]);
            }
        }
        if (w == 0) {
            if (r < 30) asm volatile("s_waitcnt vmcnt(8)" ::: "memory");
            else        asm volatile("s_waitcnt vmcnt(0)" ::: "memory");
        }
        asm volatile("s_waitcnt lgkmcnt(0)" ::: "memory");
        __builtin_amdgcn_s_barrier();
    }
    // After dummy step d=513, rm2 of wave3 lane63 = R(256,256)
    if (tid == 255) res[b] = rm2 * LN2;
}

// ---------- final mean over batches ----------
__global__ void reduce_kernel(const float* __restrict__ res, float* __restrict__ out) {
    int t = threadIdx.x;
    float v = res[t];
    #pragma unroll
    for (int off = 32; off; off >>= 1) v += __shfl_down(v, off, 64);
    if (t == 0) out[0] = v * (1.0f / BB);
}

extern "C" void kernel_launch(void* const* d_in, const int* in_sizes, int n_in,
                              void* d_out, int out_size, void* d_ws, size_t ws_size,
                              hipStream_t stream) {
    const float* S = (const float*)d_in[0];
    const float* T = (const float*)d_in[1];

    const size_t nElem  = (size_t)BB * LL * DD;                 // 16,777,216
    const size_t nDiag  = (size_t)BB * NDPAD * 256;             // 8,388,608 ushorts
    const size_t needBF = nElem * 2 * sizeof(unsigned short)
                        + nDiag * sizeof(unsigned short)
                        + ((size_t)2 * BB * LL + BB) * sizeof(float);

    if (ws_size >= needBF) {
        unsigned short* diag = (unsigned short*)d_ws;
        unsigned short* S16  = diag + nDiag;
        unsigned short* T16  = S16 + nElem;
        float* s2  = (float*)(T16 + nElem);
        float* t2  = s2 + BB * LL;
        float* rsv = t2 + BB * LL;

        prep_kernel<<<2 * BB * LL / 4, 256, 0, stream>>>(S, T, S16, T16, s2, t2);
        distmf_kernel<<<dim3(BB, 4), 256, 0, stream>>>(S16, T16, s2, t2, diag);
        sdtw_kernel<<<BB, 256, 0, stream>>>(diag, rsv);
        reduce_kernel<<<1, 64, 0, stream>>>(rsv, (float*)d_out);
    } else {
        unsigned short* diag = (unsigned short*)d_ws;
        float* s2  = (float*)(diag + nDiag);
        float* t2  = s2 + BB * LL;
        float* rsv = t2 + BB * LL;

        sqnorm_kernel<<<BB * LL, 256, 0, stream>>>(S, s2);
        sqnorm_kernel<<<BB * LL, 256, 0, stream>>>(T, t2);
        dim3 g(LL / 64, LL / 64, BB);
        dist_kernel<<<g, 256, 0, stream>>>(S, T, s2, t2, diag);
        sdtw_kernel<<<BB, 256, 0, stream>>>(diag, rsv);
        reduce_kernel<<<1, 64, 0, stream>>>(rsv, (float*)d_out);
    }
}

// Round 8
// 82.721 us; speedup vs baseline: 2.7648x; 1.2001x over previous
//
#include <hip/hip_runtime.h>
#include <math.h>

#define BB 64
#define LL 256
#define DD 1024
#define NDPAD 512   // padded anti-diagonal count per batch (511 real + 1 pad)
#define BK 32
#define LOG2E 1.4426950408889634f
#define LN2   0.6931471805599453f

typedef __attribute__((ext_vector_type(8))) short short8v;
typedef __attribute__((ext_vector_type(4))) float float4v;

__device__ __forceinline__ unsigned short f2bf(float f) {
    unsigned u = __float_as_uint(f);
    unsigned r = (u + 0x7fffu + ((u >> 16) & 1u)) >> 16;   // RNE
    return (unsigned short)r;
}
__device__ __forceinline__ float bf2f(unsigned short u) {
    return __uint_as_float(((unsigned)u) << 16);
}

// ---------- fused: fp32 load -> bf16 LDS staging + row norms + MFMA dist GEMM ----------
// 128x128 tile, BK=32, 4 waves. grid (BB, 4): batch b's tiles get linear ids
// {b, b+64, b+128, b+192} -> same XCD, so their shared fp32 row reads merge in L2.
// Epilogue stores bf16 dist * LOG2E in diag-major layout [b][i+j][j], 512-diag stride.
__global__ __launch_bounds__(256) void fused_kernel(const float* __restrict__ S,
                                                    const float* __restrict__ T,
                                                    unsigned short* __restrict__ Dd) {
    __shared__ unsigned short lds[2][2][128 * BK];   // [buf][A/B], 32 KB
    __shared__ float nrm[2][128];                    // row norms [side][local row]

    const int b    = blockIdx.x;
    const int tile = blockIdx.y;
    const int i0 = (tile & 1) * 128;
    const int j0 = (tile >> 1) * 128;
    const int tid = threadIdx.x, w = tid >> 6, lane = tid & 63;
    const int wr = w >> 1, wc = w & 1;

    const float* Sg = S + ((size_t)b * LL + i0) * DD;
    const float* Tg = T + ((size_t)b * LL + j0) * DD;

    const int sr   = w * 16 + (lane >> 2);   // staging row within 64-row half
    const int slot = lane & 3;               // lds k-slot this lane fills
    const int kb   = slot ^ (sr & 3);        // global k-block (swizzle; same for both halves)

    float4v acc[4][4];
    const float4v fzero = {0.f, 0.f, 0.f, 0.f};
    #pragma unroll
    for (int mi = 0; mi < 4; ++mi)
        #pragma unroll
        for (int ni = 0; ni < 4; ++ni) acc[mi][ni] = fzero;

    struct StgSet { float4 a[2][2]; float4 bb[2][2]; };   // [half n][8-float piece]
    StgSet st0, st1;
    float ns[2][2] = {};                      // norm accum [side][n]

    auto issue = [&](StgSet& st, int kt) {
        const float* pa = Sg + (size_t)sr * DD + kt * BK + kb * 8;
        const float* pb = Tg + (size_t)sr * DD + kt * BK + kb * 8;
        st.a[0][0]  = *(const float4*)(pa);
        st.a[0][1]  = *(const float4*)(pa + 4);
        st.a[1][0]  = *(const float4*)(pa + 64 * DD);
        st.a[1][1]  = *(const float4*)(pa + 64 * DD + 4);
        st.bb[0][0] = *(const float4*)(pb);
        st.bb[0][1] = *(const float4*)(pb + 4);
        st.bb[1][0] = *(const float4*)(pb + 64 * DD);
        st.bb[1][1] = *(const float4*)(pb + 64 * DD + 4);
    };

    auto cvtwrite = [&](const float4& v0, const float4& v1, unsigned short* dst, float& nacc) {
        nacc += v0.x * v0.x + v0.y * v0.y + v0.z * v0.z + v0.w * v0.w
              + v1.x * v1.x + v1.y * v1.y + v1.z * v1.z + v1.w * v1.w;
        uint4 o;
        o.x = ((unsigned)f2bf(v0.y) << 16) | f2bf(v0.x);
        o.y = ((unsigned)f2bf(v0.w) << 16) | f2bf(v0.z);
        o.z = ((unsigned)f2bf(v1.y) << 16) | f2bf(v1.x);
        o.w = ((unsigned)f2bf(v1.w) << 16) | f2bf(v1.z);
        *(uint4*)dst = o;
    };

    auto commit = [&](StgSet& st, int buf) {
        #pragma unroll
        for (int n = 0; n < 2; ++n) {
            cvtwrite(st.a[n][0],  st.a[n][1],  &lds[buf][0][(n * 64 + sr) * BK + slot * 8], ns[0][n]);
            cvtwrite(st.bb[n][0], st.bb[n][1], &lds[buf][1][(n * 64 + sr) * BK + slot * 8], ns[1][n]);
        }
    };

    auto compute = [&](int buf) {
        const unsigned short* LA = &lds[buf][0][0];
        const unsigned short* LB = &lds[buf][1][0];
        short8v af[4], bf[4];
        #pragma unroll
        for (int mi = 0; mi < 4; ++mi) {
            int row = wr * 64 + mi * 16 + (lane & 15);
            int kbf = (lane >> 4) ^ (row & 3);
            af[mi] = *(const short8v*)(LA + row * BK + kbf * 8);
        }
        #pragma unroll
        for (int ni = 0; ni < 4; ++ni) {
            int row = wc * 64 + ni * 16 + (lane & 15);
            int kbf = (lane >> 4) ^ (row & 3);
            bf[ni] = *(const short8v*)(LB + row * BK + kbf * 8);
        }
        #pragma unroll
        for (int mi = 0; mi < 4; ++mi)
            #pragma unroll
            for (int ni = 0; ni < 4; ++ni)
                acc[mi][ni] = __builtin_amdgcn_mfma_f32_16x16x32_bf16(af[mi], bf[ni],
                                                                      acc[mi][ni], 0, 0, 0);
    };

    issue(st0, 0);
    for (int kt2 = 0; kt2 < 32; kt2 += 2) {
        issue(st1, kt2 + 1);
        commit(st0, 0);
        __syncthreads();
        compute(0);
        if (kt2 + 2 < 32) issue(st0, kt2 + 2);
        commit(st1, 1);
        __syncthreads();
        compute(1);
    }

    // finalize row norms: reduce across the 4 slot-lanes of each row group
    #pragma unroll
    for (int side = 0; side < 2; ++side)
        #pragma unroll
        for (int n = 0; n < 2; ++n) {
            float s = ns[side][n];
            s += __shfl_xor(s, 1, 64);
            s += __shfl_xor(s, 2, 64);
            if (slot == 0) nrm[side][n * 64 + sr] = s;
        }
    __syncthreads();

    // epilogue: sq = ||s||^2 + ||t||^2 - 2*dot -> sqrt -> bf16 * LOG2E, diag-major
    const int r0 = (lane >> 4) * 4;
    const int cf = lane & 15;
    unsigned short* Db = Dd + (size_t)b * NDPAD * 256;
    #pragma unroll
    for (int mi = 0; mi < 4; ++mi) {
        #pragma unroll
        for (int ni = 0; ni < 4; ++ni) {
            int lj = wc * 64 + ni * 16 + cf;
            float tj = nrm[1][lj];
            int j = j0 + lj;
            #pragma unroll
            for (int rg = 0; rg < 4; ++rg) {
                int li = wr * 64 + mi * 16 + r0 + rg;
                float sq = nrm[0][li] + tj - 2.0f * acc[mi][ni][rg];
                float dv = sqrtf(fmaxf(sq, 1e-12f));
                int i = i0 + li;
                Db[(size_t)(i + j) * 256 + j] = f2bf(dv * LOG2E);
            }
        }
    }
}

// ---------- soft-DTW DP: 4 waves per batch, chunk-skewed wavefront ----------
// Wave w owns cols 64w+1..64w+64 (1 cell/lane). Wave w processes 16-diagonal
// chunk c during round r=c+w; boundary col values flow w -> w+1 via LDS with a
// one-round skew, so sync is ONE barrier per 16 steps.

// lane i <- lane i-1 via DPP wave_shr:1; lane 0 <- fill (old value, bound_ctrl=0)
__device__ __forceinline__ float wshr1(float src, float fill) {
    return __int_as_float(__builtin_amdgcn_update_dpp(
        __float_as_int(fill), __float_as_int(src), 0x138, 0xF, 0xF, false));
}

__global__ __launch_bounds__(256) void sdtw_kernel(const unsigned short* __restrict__ Dg,
                                                   float* __restrict__ res) {
    __shared__ unsigned short sd[8][16 * 256];   // 8 chunk buffers x 8 KB = 64 KB
    __shared__ float bbuf[3][2][16];             // boundary rings (writer waves 0..2)
    const int b = blockIdx.x;
    const int tid = threadIdx.x;
    const int w = tid >> 6;                      // wave 0..3
    const int lane = tid & 63;
    const float INF = INFINITY;
    const unsigned short* Db = Dg + (size_t)b * NDPAD * 256;

    auto prefetch = [&](int c) {
        #pragma unroll
        for (int q = 0; q < 8; ++q) {
            __builtin_amdgcn_global_load_lds(
                (const __attribute__((address_space(1))) void*)(Db + (size_t)c * 4096 + q * 512 + lane * 8),
                (__attribute__((address_space(3))) void*)(&sd[c & 7][q * 512]),
                16, 0, 0);
        }
    };

    const int col0 = 64 * w + lane;              // 0-based column (j-1)
    float rm1 = INF, rm2 = INF;
    float p2carry = (tid == 0) ? 0.0f : INF;     // R(0,0) seed for wave0 lane0
    float bcarry = INF;

    if (w == 0) {
        prefetch(0);
        prefetch(1);
        asm volatile("s_waitcnt vmcnt(8)" ::: "memory");   // chunk 0 landed
    }
    asm volatile("s_waitcnt lgkmcnt(0)" ::: "memory");
    __builtin_amdgcn_s_barrier();

    for (int r = 0; r < 35; ++r) {
        if (w == 0 && r + 2 < 32) prefetch(r + 2);
        const int c = r - w;
        if (0 <= c && c < 32) {
            const unsigned short* Lp = &sd[c & 7][0];
            float dv[16];
            #pragma unroll
            for (int q = 0; q < 16; ++q)
                dv[q] = bf2f(Lp[q * 256 + col0]);

            float bv[16];
            if (w == 0) {
                #pragma unroll
                for (int q = 0; q < 16; ++q) bv[q] = INF;
            } else {
                const float4* bp4 = (const float4*)&bbuf[w - 1][c & 1][0];
                float4 b0 = bp4[0], b1 = bp4[1], b2 = bp4[2], b3 = bp4[3];
                bv[0] = bcarry;
                bv[1] = b0.x;  bv[2] = b0.y;  bv[3] = b0.z;  bv[4] = b0.w;
                bv[5] = b1.x;  bv[6] = b1.y;  bv[7] = b1.z;  bv[8] = b1.w;
                bv[9] = b2.x;  bv[10] = b2.y; bv[11] = b2.z; bv[12] = b2.w;
                bv[13] = b3.x; bv[14] = b3.y; bv[15] = b3.z;
                bcarry = b3.w;
            }
            asm volatile("s_waitcnt lgkmcnt(0)" ::: "memory");
            __builtin_amdgcn_sched_barrier(0);

            const int ibase = 16 * c - col0;     // (i-1) at q=0
            float bb[16];
            #pragma unroll
            for (int q = 0; q < 16; ++q) {
                float p1 = wshr1(rm1, bv[q]);    // left neighbor's diag d-1
                float p2 = p2carry;              // left neighbor's diag d-2
                p2carry = p1;
                float m   = fminf(p2, fminf(rm1, p1));
                float mid = __builtin_amdgcn_fmed3f(p2, rm1, p1);
                float M   = fmaxf(p2, fmaxf(rm1, p1));
                float s   = (__builtin_amdgcn_exp2f(m - mid) +
                             __builtin_amdgcn_exp2f(m - M)) + 1.0f;
                float rcv = dv[q] + m - __builtin_amdgcn_logf(s);
                bool valid = (unsigned)(ibase + q) < 256u;
                rcv = valid ? rcv : INF;
                rm2 = rm1;
                rm1 = rcv;
                bb[q] = rcv;
            }
            if (w < 3 && lane == 63) {           // publish 16 boundary values
                float4* op = (float4*)&bbuf[w][c & 1][0];
                op[0] = make_float4(bb[0], bb[1], bb[2], bb[3]);
                op[1] = make_float4(bb[4], bb[5], bb[6], bb[7]);
                op[2] = make_float4(bb[8], bb[9], bb[10], bb[11]);
                op[3] = make_float4(bb[12], bb[13], bb[14], bb[15]);
            }
        }
        if (w == 0) {
            if (r < 30) asm volatile("s_waitcnt vmcnt(8)" ::: "memory");
            else        asm volatile("s_waitcnt vmcnt(0)" ::: "memory");
        }
        asm volatile("s_waitcnt lgkmcnt(0)" ::: "memory");
        __builtin_amdgcn_s_barrier();
    }
    // After dummy step d=513, rm2 of wave3 lane63 = R(256,256)
    if (tid == 255) res[b] = rm2 * LN2;
}

// ---------- final mean over batches ----------
__global__ void reduce_kernel(const float* __restrict__ res, float* __restrict__ out) {
    int t = threadIdx.x;
    float v = res[t];
    #pragma unroll
    for (int off = 32; off; off >>= 1) v += __shfl_down(v, off, 64);
    if (t == 0) out[0] = v * (1.0f / BB);
}

extern "C" void kernel_launch(void* const* d_in, const int* in_sizes, int n_in,
                              void* d_out, int out_size, void* d_ws, size_t ws_size,
                              hipStream_t stream) {
    const float* S = (const float*)d_in[0];
    const float* T = (const float*)d_in[1];

    const size_t nDiag = (size_t)BB * NDPAD * 256;   // 8,388,608 ushorts (16.8 MB)
    unsigned short* diag = (unsigned short*)d_ws;
    float* rsv = (float*)(diag + nDiag);

    fused_kernel<<<dim3(BB, 4), 256, 0, stream>>>(S, T, diag);
    sdtw_kernel<<<BB, 256, 0, stream>>>(diag, rsv);
    reduce_kernel<<<1, 64, 0, stream>>>(rsv, (float*)d_out);
}